// Round 12
// baseline (302.778 us; speedup 1.0000x reference)
//
#include <hip/hip_runtime.h>

// Attention_13632226198096: B=4, S=2048, D=1024 fp32 single-head attention.
// Round 12: r9 pipeline (proven 164 µs) with ONE change — proj_gemm at
// __launch_bounds__(256,5): 5 blocks/CU (32 KB LDS x5 = 160 KB exact),
// 1536 blocks / 1280 slots = 1.2 rounds vs 1.5 -> less grid quantization.
// QK: 256^2 4-phase fp16-out. PV: 128^2 2-phase. row&7 XOR swizzle (BK=64
// only — BK=32 is structurally conflicted within 16-lane issue groups).

typedef unsigned short ushort_t;
typedef __bf16 bf16x8 __attribute__((ext_vector_type(8)));
typedef float f32x4 __attribute__((ext_vector_type(4)));
typedef _Float16 h8 __attribute__((ext_vector_type(8)));
typedef short short8v __attribute__((ext_vector_type(8)));

__device__ __forceinline__ unsigned short f2bf(float f) {
  unsigned u = __builtin_bit_cast(unsigned, f);
  u += 0x7fffu + ((u >> 16) & 1u);
  return (unsigned short)(u >> 16);
}

// ---------------------------------------------------------------------------
// proj_gemm (m97 structure, 5 blocks/CU): C[8192,3072] = xb @ w3^T + bcat,
// split into q / k (row-major bf16) and vt (v transposed, [4][1024][2048]).
// 128x128 tile, BK=64, 256 thr = 4 waves (2x2), 32 KB LDS, 2-barrier loop.
// ---------------------------------------------------------------------------
__global__ __launch_bounds__(256, 5)
void proj_gemm(const ushort_t* __restrict__ A, int lda,
               const ushort_t* __restrict__ Bm, int ldb,
               ushort_t* __restrict__ Cq, ushort_t* __restrict__ Ck,
               ushort_t* __restrict__ Cvt, int K,
               const float* __restrict__ bias)
{
  __shared__ ushort_t smA[128 * 64] __attribute__((aligned(16)));
  __shared__ ushort_t smB[128 * 64] __attribute__((aligned(16)));

  constexpr int RX = 4, RY = 8, BPR = RX * RY;
  const int gx = gridDim.x;
  const int lin = blockIdx.y * gx + blockIdx.x;
  const int xcd = lin & 7, s = lin >> 3;
  const int chunk = s / BPR, idx = s % BPR;
  const int rect = chunk * 8 + xcd;
  const int nrx = gx / RX;
  const int bx = (rect % nrx) * RX + (idx % RX);
  const int by = (rect / nrx) * RY + (idx / RX);

  const int row0 = by * 128, col0 = bx * 128;

  const int tid = threadIdx.x;
  const int wave = tid >> 6, lane = tid & 63;
  const int wr = (wave >> 1) * 64, wc = (wave & 1) * 64;
  const int l15 = lane & 15;

  // staging: thread t -> row t>>3 (0..31, +i*32), swizzled col
  const int srow = tid >> 3;
  const int scol = ((tid & 7) ^ (srow & 7)) * 8;
  const ushort_t* ag = A  + (long long)(row0 + srow) * lda + scol;
  const ushort_t* bg = Bm + (long long)(col0 + srow) * ldb + scol;
  ushort_t* ldsA = &smA[(wave * 8) * 64];   // wave-uniform base
  ushort_t* ldsB = &smB[(wave * 8) * 64];

  f32x4 acc[4][4];
#pragma unroll
  for (int m = 0; m < 4; ++m)
#pragma unroll
    for (int n = 0; n < 4; ++n)
#pragma unroll
      for (int j = 0; j < 4; ++j) acc[m][n][j] = 0.f;

  for (int k0 = 0; k0 < K; k0 += 64) {
#pragma unroll
    for (int i = 0; i < 4; ++i) {
      __builtin_amdgcn_global_load_lds(
          (const __attribute__((address_space(1))) void*)(ag + (long long)i * 32 * lda + k0),
          (__attribute__((address_space(3))) void*)(ldsA + i * 32 * 64), 16, 0, 0);
      __builtin_amdgcn_global_load_lds(
          (const __attribute__((address_space(1))) void*)(bg + (long long)i * 32 * ldb + k0),
          (__attribute__((address_space(3))) void*)(ldsB + i * 32 * 64), 16, 0, 0);
    }
    __syncthreads();   // drains vmcnt + lgkm
#pragma unroll
    for (int kk = 0; kk < 2; ++kk) {
      const int kx = (((lane >> 4) + 4 * kk) ^ (l15 & 7)) * 8;
      bf16x8 af[4], bfv[4];
#pragma unroll
      for (int m = 0; m < 4; ++m)
        af[m] = *(const bf16x8*)&smA[(wr + m * 16 + l15) * 64 + kx];
#pragma unroll
      for (int n = 0; n < 4; ++n)
        bfv[n] = *(const bf16x8*)&smB[(wc + n * 16 + l15) * 64 + kx];
#pragma unroll
      for (int m = 0; m < 4; ++m)
#pragma unroll
        for (int n = 0; n < 4; ++n)
          acc[m][n] = __builtin_amdgcn_mfma_f32_16x16x32_bf16(af[m], bfv[n], acc[m][n], 0, 0, 0);
    }
    __syncthreads();
  }

  // epilogue: C/D layout col=lane&15, row=(lane>>4)*4+j; sel uniform/block
  const int r4 = (lane >> 4) * 4;
  const int sel = col0 >> 10;
#pragma unroll
  for (int n = 0; n < 4; ++n) {
    const int cg = col0 + wc + n * 16 + l15;
    const int col = cg & 1023;
    const float badd = bias[cg];
    if (sel < 2) {
      ushort_t* outp = (sel == 0) ? Cq : Ck;
#pragma unroll
      for (int m = 0; m < 4; ++m)
#pragma unroll
        for (int j = 0; j < 4; ++j) {
          const long long rg = row0 + wr + m * 16 + r4 + j;
          outp[rg * 1024 + col] = f2bf(acc[m][n][j] + badd);
        }
    } else {
#pragma unroll
      for (int m = 0; m < 4; ++m) {
        const long long rg = row0 + wr + m * 16 + r4;
        const long long b = rg >> 11, srw = rg & 2047;
        ushort4 o;
        o.x = f2bf(acc[m][n][0] + badd);
        o.y = f2bf(acc[m][n][1] + badd);
        o.z = f2bf(acc[m][n][2] + badd);
        o.w = f2bf(acc[m][n][3] + badd);
        *(ushort4*)&Cvt[b * 2097152 + (long long)col * 2048 + srw] = o;
      }
    }
  }
}

// ---------------------------------------------------------------------------
// pv_gemm: 128x128 tile, 2-phase, 64 KB LDS, 2 blocks/CU (r9, proven).
// ---------------------------------------------------------------------------
template<int RX, int RY>
__global__ __launch_bounds__(512, 4)
void pv_gemm(const ushort_t* __restrict__ A, long long sAz, int lda,
             const ushort_t* __restrict__ Bm, long long sBz, int ldb,
             float* __restrict__ C0, long long sCz, int ldc, int K)
{
  constexpr int SLOT = 8192;
  constexpr int BUF  = 2 * SLOT;
  __shared__ ushort_t lds_[2 * BUF] __attribute__((aligned(16)));

  constexpr int BPR = RX * RY;
  const int gx = gridDim.x;
  const int lin = blockIdx.y * gx + blockIdx.x;
  const int xcd = lin & 7, s = lin >> 3;
  const int chunk = s / BPR, idx = s % BPR;
  const int rect = chunk * 8 + xcd;
  const int nrx = gx / RX;
  const int bx = (rect % nrx) * RX + (idx % RX);
  const int by = (rect / nrx) * RY + (idx / RX);

  const int z = blockIdx.z;
  const ushort_t* Ab = A  + (long long)z * sAz + (long long)by * 128 * lda;
  const ushort_t* Bb = Bm + (long long)z * sBz + (long long)bx * 128 * ldb;

  const int tid = threadIdx.x, wid = tid >> 6, lane = tid & 63;
  const int wr = wid >> 2, wc = wid & 3;
  const int l15 = lane & 15;
  const int kx0 = (((lane >> 4) + 0) ^ (l15 & 7)) * 8;
  const int kx1 = (((lane >> 4) + 4) ^ (l15 & 7)) * 8;
  const int srow = lane >> 3;
  const int scol = ((lane & 7) ^ (srow & 7)) * 8;

  const ushort_t* agA = Ab + (long long)(wid * 8 + srow) * lda + scol;
  const ushort_t* agB = Bb + (long long)(wid * 8 + srow) * ldb + scol;
  const long long jA = (long long)64 * lda, jB = (long long)64 * ldb;
  const int ldsA0 = wid * 512;
  const int ldsB0 = SLOT + wid * 512;

  auto stage = [&](const ushort_t* g, long long jstep, int ldsOff) {
#pragma unroll
    for (int j = 0; j < 2; ++j)
      __builtin_amdgcn_global_load_lds(
          (const __attribute__((address_space(1))) void*)(g + j * jstep),
          (__attribute__((address_space(3))) void*)(&lds_[ldsOff + j * 4096]),
          16, 0, 0);
  };

  f32x4 acc[4][2];
#pragma unroll
  for (int m = 0; m < 4; ++m)
#pragma unroll
    for (int n = 0; n < 2; ++n)
#pragma unroll
      for (int j = 0; j < 4; ++j) acc[m][n][j] = 0.f;

  stage(agA, jA, 0 * BUF + ldsA0); agA += 64;
  stage(agB, jB, 0 * BUF + ldsB0); agB += 64;
  stage(agA, jA, 1 * BUF + ldsA0); agA += 64;
  stage(agB, jB, 1 * BUF + ldsB0); agB += 64;
  asm volatile("s_waitcnt vmcnt(4)" ::: "memory");
  __builtin_amdgcn_s_barrier();

  const int NT = K >> 6;
  bf16x8 a0[4], a1[4], bf[2];

  for (int t = 0; t < NT; ++t) {
    const int q = t & 1;
    const ushort_t* Al = &lds_[q * BUF] + wr * 4096;
    const ushort_t* Bl = &lds_[q * BUF + SLOT] + wc * 2048;

#pragma unroll
    for (int m = 0; m < 4; ++m) a0[m] = *(const bf16x8*)(Al + (m * 16 + l15) * 64 + kx0);
#pragma unroll
    for (int n = 0; n < 2; ++n) bf[n] = *(const bf16x8*)(Bl + (n * 16 + l15) * 64 + kx0);
#pragma unroll
    for (int m = 0; m < 4; ++m) a1[m] = *(const bf16x8*)(Al + (m * 16 + l15) * 64 + kx1);
    __builtin_amdgcn_s_barrier();
    __builtin_amdgcn_s_setprio(1);
#pragma unroll
    for (int m = 0; m < 4; ++m)
#pragma unroll
      for (int n = 0; n < 2; ++n)
        acc[m][n] = __builtin_amdgcn_mfma_f32_16x16x32_bf16(a0[m], bf[n], acc[m][n], 0, 0, 0);
    __builtin_amdgcn_s_setprio(0);
    __builtin_amdgcn_s_barrier();

#pragma unroll
    for (int n = 0; n < 2; ++n) bf[n] = *(const bf16x8*)(Bl + (n * 16 + l15) * 64 + kx1);
    asm volatile("s_waitcnt lgkmcnt(0)" ::: "memory");
    __builtin_amdgcn_sched_barrier(0);
    if (t + 2 < NT) {
      stage(agA, jA, q * BUF + ldsA0); agA += 64;
      stage(agB, jB, q * BUF + ldsB0); agB += 64;
    }
    __builtin_amdgcn_s_barrier();
    __builtin_amdgcn_s_setprio(1);
#pragma unroll
    for (int m = 0; m < 4; ++m)
#pragma unroll
      for (int n = 0; n < 2; ++n)
        acc[m][n] = __builtin_amdgcn_mfma_f32_16x16x32_bf16(a1[m], bf[n], acc[m][n], 0, 0, 0);
    __builtin_amdgcn_s_setprio(0);
    if (t < NT - 2)       asm volatile("s_waitcnt vmcnt(4)" ::: "memory");
    else if (t == NT - 2) asm volatile("s_waitcnt vmcnt(0)" ::: "memory");
    __builtin_amdgcn_s_barrier();
  }

  const int r4 = (lane >> 4) * 4;
  const long long crow0 = (long long)by * 128 + wr * 64;
  const int ccol0 = bx * 128 + wc * 32;
#pragma unroll
  for (int n = 0; n < 2; ++n) {
    const int cg = ccol0 + n * 16 + l15;
#pragma unroll
    for (int m = 0; m < 4; ++m)
#pragma unroll
      for (int j = 0; j < 4; ++j) {
        const long long rg = crow0 + m * 16 + r4 + j;
        C0[(long long)z * sCz + rg * ldc + cg] = acc[m][n][j];
      }
  }
}

// ---------------------------------------------------------------------------
// qk_gemm: 256x256 tile, 4-phase; fp16 scores out (r8/r9, proven).
// ---------------------------------------------------------------------------
__global__ __launch_bounds__(512, 1)
void qk_gemm(const ushort_t* __restrict__ A, long long sAz, int lda,
             const ushort_t* __restrict__ Bm, long long sBz, int ldb,
             _Float16* __restrict__ C, long long sCz, int ldc,
             int K, float scale)
{
  constexpr int AH = 8192, BH = 8192, BUF = 2 * AH + 2 * BH;
  constexpr int RX = 4, RY = 2, BPR = RX * RY;
  __shared__ ushort_t lds_[2 * BUF] __attribute__((aligned(16)));

  const int gx = gridDim.x;
  const int lin = blockIdx.y * gx + blockIdx.x;
  const int xcd = lin & 7, s = lin >> 3;
  const int chunk = s / BPR, idx = s % BPR;
  const int rect = chunk * 8 + xcd;
  const int nrx = gx / RX;
  const int bx = (rect % nrx) * RX + (idx % RX);
  const int by = (rect / nrx) * RY + (idx / RX);

  const int z = blockIdx.z;
  const ushort_t* Ab = A  + (long long)z * sAz + (long long)by * 256 * lda;
  const ushort_t* Bb = Bm + (long long)z * sBz + (long long)bx * 256 * ldb;

  const int tid = threadIdx.x, wid = tid >> 6, lane = tid & 63;
  const int wr = wid >> 2, wc = wid & 3;
  const int l15 = lane & 15;
  const int kx0 = (((lane >> 4) + 0) ^ (l15 & 7)) * 8;
  const int kx1 = (((lane >> 4) + 4) ^ (l15 & 7)) * 8;
  const int srow = lane >> 3;
  const int scol = ((lane & 7) ^ (srow & 7)) * 8;

  const ushort_t* agA = Ab + (long long)(wid * 16 + srow) * lda + scol;
  const ushort_t* agB = Bb + (long long)(wid * 16 + srow) * ldb + scol;

  auto stageA = [&](int q) {
#pragma unroll
    for (int h = 0; h < 2; ++h)
#pragma unroll
      for (int j = 0; j < 2; ++j)
        __builtin_amdgcn_global_load_lds(
            (const __attribute__((address_space(1))) void*)(agA + (long long)(h * 128 + j * 8) * lda),
            (__attribute__((address_space(3))) void*)
              (&lds_[q * BUF + h * AH + (wid * 128 + j * 64) * 8]),
            16, 0, 0);
  };
  auto stageB = [&](int q) {
#pragma unroll
    for (int h = 0; h < 2; ++h)
#pragma unroll
      for (int j = 0; j < 2; ++j)
        __builtin_amdgcn_global_load_lds(
            (const __attribute__((address_space(1))) void*)(agB + (long long)(h * 128 + j * 8) * ldb),
            (__attribute__((address_space(3))) void*)
              (&lds_[q * BUF + 2 * AH + h * BH + (wid * 128 + j * 64) * 8]),
            16, 0, 0);
  };

  f32x4 acc[8][4];
#pragma unroll
  for (int m = 0; m < 8; ++m)
#pragma unroll
    for (int n = 0; n < 4; ++n)
#pragma unroll
      for (int j = 0; j < 4; ++j) acc[m][n][j] = 0.f;

  stageA(0); stageB(0); agA += 64; agB += 64;
  stageA(1); stageB(1); agA += 64; agB += 64;
  asm volatile("s_waitcnt vmcnt(8)" ::: "memory");
  __builtin_amdgcn_s_barrier();

  const int NT = K >> 6;
  bf16x8 af[4], bf[4];

  for (int t = 0; t < NT; ++t) {
    const int q = t & 1;
    const ushort_t* Al = &lds_[q * BUF + wr * AH];
    const ushort_t* Bl = &lds_[q * BUF + 2 * AH + (wc >> 1) * BH + (wc & 1) * 4096];

    // ph1
#pragma unroll
    for (int n = 0; n < 4; ++n) bf[n] = *(const bf16x8*)(Bl + (n * 16 + l15) * 64 + kx0);
#pragma unroll
    for (int m = 0; m < 4; ++m) af[m] = *(const bf16x8*)(Al + (m * 16 + l15) * 64 + kx0);
    __builtin_amdgcn_s_barrier();
    __builtin_amdgcn_s_setprio(1);
#pragma unroll
    for (int m = 0; m < 4; ++m)
#pragma unroll
      for (int n = 0; n < 4; ++n)
        acc[m][n] = __builtin_amdgcn_mfma_f32_16x16x32_bf16(af[m], bf[n], acc[m][n], 0, 0, 0);
    __builtin_amdgcn_s_setprio(0);
    __builtin_amdgcn_s_barrier();

    // ph2
#pragma unroll
    for (int m = 0; m < 4; ++m) af[m] = *(const bf16x8*)(Al + ((4 + m) * 16 + l15) * 64 + kx0);
    __builtin_amdgcn_s_barrier();
    __builtin_amdgcn_s_setprio(1);
#pragma unroll
    for (int m = 0; m < 4; ++m)
#pragma unroll
      for (int n = 0; n < 4; ++n)
        acc[4 + m][n] = __builtin_amdgcn_mfma_f32_16x16x32_bf16(af[m], bf[n], acc[4 + m][n], 0, 0, 0);
    __builtin_amdgcn_s_setprio(0);
    __builtin_amdgcn_s_barrier();

    // ph3
#pragma unroll
    for (int n = 0; n < 4; ++n) bf[n] = *(const bf16x8*)(Bl + (n * 16 + l15) * 64 + kx1);
#pragma unroll
    for (int m = 0; m < 4; ++m) af[m] = *(const bf16x8*)(Al + (m * 16 + l15) * 64 + kx1);
    __builtin_amdgcn_s_barrier();
    __builtin_amdgcn_s_setprio(1);
#pragma unroll
    for (int m = 0; m < 4; ++m)
#pragma unroll
      for (int n = 0; n < 4; ++n)
        acc[m][n] = __builtin_amdgcn_mfma_f32_16x16x32_bf16(af[m], bf[n], acc[m][n], 0, 0, 0);
    __builtin_amdgcn_s_setprio(0);
    __builtin_amdgcn_s_barrier();

    // ph4 + staged prefetch after lgkm drain
#pragma unroll
    for (int m = 0; m < 4; ++m) af[m] = *(const bf16x8*)(Al + ((4 + m) * 16 + l15) * 64 + kx1);
    asm volatile("s_waitcnt lgkmcnt(0)" ::: "memory");
    __builtin_amdgcn_sched_barrier(0);
    if (t + 2 < NT) { stageA(q); stageB(q); agA += 64; agB += 64; }
    __builtin_amdgcn_s_barrier();
    __builtin_amdgcn_s_setprio(1);
#pragma unroll
    for (int m = 0; m < 4; ++m)
#pragma unroll
      for (int n = 0; n < 4; ++n)
        acc[4 + m][n] = __builtin_amdgcn_mfma_f32_16x16x32_bf16(af[m], bf[n], acc[4 + m][n], 0, 0, 0);
    __builtin_amdgcn_s_setprio(0);
    if (t < NT - 2)       asm volatile("s_waitcnt vmcnt(8)" ::: "memory");
    else if (t == NT - 2) asm volatile("s_waitcnt vmcnt(0)" ::: "memory");
    __builtin_amdgcn_s_barrier();
  }

  const int r4 = (lane >> 4) * 4;
  const long long crow0 = (long long)by * 256 + wr * 128;
  const int ccol0 = bx * 256 + wc * 64;
#pragma unroll
  for (int n = 0; n < 4; ++n) {
    const int cg = ccol0 + n * 16 + l15;
#pragma unroll
    for (int m = 0; m < 8; ++m)
#pragma unroll
      for (int j = 0; j < 4; ++j) {
        const long long rg = crow0 + m * 16 + r4 + j;
        C[(long long)z * sCz + rg * ldc + cg] = (_Float16)(acc[m][n][j] * scale);
      }
  }
}

// ---------------------------------------------------------------------------
__global__ __launch_bounds__(256)
void cast_f32_bf16(const float* __restrict__ in, ushort_t* __restrict__ out, long long n)
{
  long long i = ((long long)blockIdx.x * blockDim.x + threadIdx.x) * 4;
  const long long stride = (long long)gridDim.x * blockDim.x * 4;
  for (; i < n; i += stride) {
    const float4 v = *(const float4*)&in[i];
    ushort4 o;
    o.x = f2bf(v.x); o.y = f2bf(v.y); o.z = f2bf(v.z); o.w = f2bf(v.w);
    *(ushort4*)&out[i] = o;
  }
}

__global__ __launch_bounds__(256)
void prep_w(const float* __restrict__ Wq, const float* __restrict__ Wk,
            const float* __restrict__ Wv, const float* __restrict__ bq,
            const float* __restrict__ bk, const float* __restrict__ bv,
            ushort_t* __restrict__ w3, float* __restrict__ bcat)
{
  const int which = blockIdx.x >> 10;
  const float* W = (which == 0) ? Wq : (which == 1) ? Wk : Wv;
  const long long i = ((long long)(blockIdx.x & 1023) * 256 + threadIdx.x) * 4;
  const float4 v = *(const float4*)&W[i];
  ushort4 o;
  o.x = f2bf(v.x); o.y = f2bf(v.y); o.z = f2bf(v.z); o.w = f2bf(v.w);
  *(ushort4*)&w3[(long long)which * 1024 * 1024 + i] = o;
  const int g = blockIdx.x * 256 + threadIdx.x;
  if (g < 3072) bcat[g] = (g < 1024) ? bq[g] : (g < 2048) ? bk[g - 1024] : bv[g - 2048];
}

// row softmax over 2048 fp16 -> bf16, one block (256 thr) per row
__global__ __launch_bounds__(256)
void softmax2048(const _Float16* __restrict__ Sc, ushort_t* __restrict__ P)
{
  const long long row = blockIdx.x;
  const _Float16* s = Sc + row * 2048;
  const int tid = threadIdx.x;
  const int wave = tid >> 6, lane = tid & 63;

  const h8 a = *(const h8*)&s[tid * 8];
  float f[8];
#pragma unroll
  for (int i = 0; i < 8; ++i) f[i] = (float)a[i];
  float m = fmaxf(fmaxf(fmaxf(f[0], f[1]), fmaxf(f[2], f[3])),
                  fmaxf(fmaxf(f[4], f[5]), fmaxf(f[6], f[7])));
#pragma unroll
  for (int off = 32; off > 0; off >>= 1) m = fmaxf(m, __shfl_xor(m, off));
  __shared__ float redm[4], reds[4];
  if (lane == 0) redm[wave] = m;
  __syncthreads();
  m = fmaxf(fmaxf(redm[0], redm[1]), fmaxf(redm[2], redm[3]));

  float e[8];
#pragma unroll
  for (int i = 0; i < 8; ++i) e[i] = __expf(f[i] - m);
  float sum = ((e[0] + e[1]) + (e[2] + e[3])) + ((e[4] + e[5]) + (e[6] + e[7]));
#pragma unroll
  for (int off = 32; off > 0; off >>= 1) sum += __shfl_xor(sum, off);
  if (lane == 0) reds[wave] = sum;
  __syncthreads();
  sum = (reds[0] + reds[1]) + (reds[2] + reds[3]);
  const float inv = 1.0f / sum;

  short8v o;
#pragma unroll
  for (int i = 0; i < 8; ++i) o[i] = (short)f2bf(e[i] * inv);
  *(short8v*)&P[row * 2048 + tid * 8] = o;
}

// ---------------------------------------------------------------------------
extern "C" void kernel_launch(void* const* d_in, const int* in_sizes, int n_in,
                              void* d_out, int out_size, void* d_ws, size_t ws_size,
                              hipStream_t stream)
{
  constexpr int B = 4, S = 2048, D = 1024;
  constexpr long long MT = (long long)B * S;
  constexpr long long SD = (long long)S * D;
  constexpr long long SS = (long long)S * S;

  const float* x  = (const float*)d_in[0];
  const float* Wq = (const float*)d_in[1];
  const float* bq = (const float*)d_in[2];
  const float* Wk = (const float*)d_in[3];
  const float* bk = (const float*)d_in[4];
  const float* Wv = (const float*)d_in[5];
  const float* bv = (const float*)d_in[6];
  float* out = (float*)d_out;

  // ws layout (bytes)
  char* base = (char*)d_ws;
  ushort_t*  q       = (ushort_t*)(base);               // 16777216
  ushort_t*  k       = (ushort_t*)(base + 16777216);    // 16777216
  ushort_t*  vt      = (ushort_t*)(base + 33554432);    // 16777216  [4][1024][2048]
  _Float16*  scores  = (_Float16*)(base + 50331648);    // 33554432  fp16
  ushort_t*  P       = (ushort_t*)(base + 117440512);   // 33554432
  ushort_t*  xb      = (ushort_t*)(base + 83886080);    // 16777216
  ushort_t*  w3      = (ushort_t*)(base + 100663296);   // 6291456
  float*     bcat    = (float*)   (base + 106954752);   // 12288

  // 1) casts
  cast_f32_bf16<<<2048, 256, 0, stream>>>(x, xb, MT * D);
  prep_w<<<3072, 256, 0, stream>>>(Wq, Wk, Wv, bq, bk, bv, w3, bcat);

  // 2) fused QKV projection (m97 structure, 5 blocks/CU) -> q, k, vt
  proj_gemm<<<dim3(24, 64, 1), 256, 0, stream>>>(
      xb, D, w3, D, q, k, vt, D, bcat);

  // 3) QK^T: scores[z] = (q @ k^T) / 32  (fp16 out)
  qk_gemm<<<dim3(8, 8, 4), 512, 0, stream>>>(
      q, SD, D, k, SD, D, scores, SS, S, D, 0.03125f);

  // 4) softmax rows (fp16 in, bf16 out)
  softmax2048<<<MT, 256, 0, stream>>>(scores, P);

  // 5) PV: out[z] = P @ vt^T
  pv_gemm<2, 4><<<dim3(8, 16, 4), 512, 0, stream>>>(
      P, SS, S, vt, (long long)D * S, S, out, SD, D, S);
}

// Round 13
// 162.984 us; speedup vs baseline: 1.8577x; 1.8577x over previous
//
#include <hip/hip_runtime.h>

// Attention_13632226198096: B=4, S=2048, D=1024 fp32 single-head attention.
// Round 13: revert to r9 (proven 164.3 µs) + merge the two prep casts into
// one dispatch. proj: m97 structure (256,4). QK: 256^2 4-phase fp16-out.
// PV: 128^2 2-phase. Conflict-free row&7 XOR LDS swizzle everywhere.
// r12 lesson: (256,5) forces VGPR 48 < ~110 working set -> scratch spill
// (587 MB writes); never cap below the register floor.

typedef unsigned short ushort_t;
typedef __bf16 bf16x8 __attribute__((ext_vector_type(8)));
typedef float f32x4 __attribute__((ext_vector_type(4)));
typedef _Float16 h8 __attribute__((ext_vector_type(8)));
typedef short short8v __attribute__((ext_vector_type(8)));

__device__ __forceinline__ unsigned short f2bf(float f) {
  unsigned u = __builtin_bit_cast(unsigned, f);
  u += 0x7fffu + ((u >> 16) & 1u);
  return (unsigned short)(u >> 16);
}

// ---------------------------------------------------------------------------
// proj_gemm (m97 structure, 4 blocks/CU): C[8192,3072] = xb @ w3^T + bcat,
// split into q / k (row-major bf16) and vt (v transposed, [4][1024][2048]).
// 128x128 tile, BK=64, 256 thr = 4 waves (2x2), 32 KB LDS, 2-barrier loop.
// ---------------------------------------------------------------------------
__global__ __launch_bounds__(256, 4)
void proj_gemm(const ushort_t* __restrict__ A, int lda,
               const ushort_t* __restrict__ Bm, int ldb,
               ushort_t* __restrict__ Cq, ushort_t* __restrict__ Ck,
               ushort_t* __restrict__ Cvt, int K,
               const float* __restrict__ bias)
{
  __shared__ ushort_t smA[128 * 64] __attribute__((aligned(16)));
  __shared__ ushort_t smB[128 * 64] __attribute__((aligned(16)));

  constexpr int RX = 4, RY = 8, BPR = RX * RY;
  const int gx = gridDim.x;
  const int lin = blockIdx.y * gx + blockIdx.x;
  const int xcd = lin & 7, s = lin >> 3;
  const int chunk = s / BPR, idx = s % BPR;
  const int rect = chunk * 8 + xcd;
  const int nrx = gx / RX;
  const int bx = (rect % nrx) * RX + (idx % RX);
  const int by = (rect / nrx) * RY + (idx / RX);

  const int row0 = by * 128, col0 = bx * 128;

  const int tid = threadIdx.x;
  const int wave = tid >> 6, lane = tid & 63;
  const int wr = (wave >> 1) * 64, wc = (wave & 1) * 64;
  const int l15 = lane & 15;

  // staging: thread t -> row t>>3 (0..31, +i*32), swizzled col
  const int srow = tid >> 3;
  const int scol = ((tid & 7) ^ (srow & 7)) * 8;
  const ushort_t* ag = A  + (long long)(row0 + srow) * lda + scol;
  const ushort_t* bg = Bm + (long long)(col0 + srow) * ldb + scol;
  ushort_t* ldsA = &smA[(wave * 8) * 64];   // wave-uniform base
  ushort_t* ldsB = &smB[(wave * 8) * 64];

  f32x4 acc[4][4];
#pragma unroll
  for (int m = 0; m < 4; ++m)
#pragma unroll
    for (int n = 0; n < 4; ++n)
#pragma unroll
      for (int j = 0; j < 4; ++j) acc[m][n][j] = 0.f;

  for (int k0 = 0; k0 < K; k0 += 64) {
#pragma unroll
    for (int i = 0; i < 4; ++i) {
      __builtin_amdgcn_global_load_lds(
          (const __attribute__((address_space(1))) void*)(ag + (long long)i * 32 * lda + k0),
          (__attribute__((address_space(3))) void*)(ldsA + i * 32 * 64), 16, 0, 0);
      __builtin_amdgcn_global_load_lds(
          (const __attribute__((address_space(1))) void*)(bg + (long long)i * 32 * ldb + k0),
          (__attribute__((address_space(3))) void*)(ldsB + i * 32 * 64), 16, 0, 0);
    }
    __syncthreads();   // drains vmcnt + lgkm
#pragma unroll
    for (int kk = 0; kk < 2; ++kk) {
      const int kx = (((lane >> 4) + 4 * kk) ^ (l15 & 7)) * 8;
      bf16x8 af[4], bfv[4];
#pragma unroll
      for (int m = 0; m < 4; ++m)
        af[m] = *(const bf16x8*)&smA[(wr + m * 16 + l15) * 64 + kx];
#pragma unroll
      for (int n = 0; n < 4; ++n)
        bfv[n] = *(const bf16x8*)&smB[(wc + n * 16 + l15) * 64 + kx];
#pragma unroll
      for (int m = 0; m < 4; ++m)
#pragma unroll
        for (int n = 0; n < 4; ++n)
          acc[m][n] = __builtin_amdgcn_mfma_f32_16x16x32_bf16(af[m], bfv[n], acc[m][n], 0, 0, 0);
    }
    __syncthreads();
  }

  // epilogue: C/D layout col=lane&15, row=(lane>>4)*4+j; sel uniform/block
  const int r4 = (lane >> 4) * 4;
  const int sel = col0 >> 10;
#pragma unroll
  for (int n = 0; n < 4; ++n) {
    const int cg = col0 + wc + n * 16 + l15;
    const int col = cg & 1023;
    const float badd = bias[cg];
    if (sel < 2) {
      ushort_t* outp = (sel == 0) ? Cq : Ck;
#pragma unroll
      for (int m = 0; m < 4; ++m)
#pragma unroll
        for (int j = 0; j < 4; ++j) {
          const long long rg = row0 + wr + m * 16 + r4 + j;
          outp[rg * 1024 + col] = f2bf(acc[m][n][j] + badd);
        }
    } else {
#pragma unroll
      for (int m = 0; m < 4; ++m) {
        const long long rg = row0 + wr + m * 16 + r4;
        const long long b = rg >> 11, srw = rg & 2047;
        ushort4 o;
        o.x = f2bf(acc[m][n][0] + badd);
        o.y = f2bf(acc[m][n][1] + badd);
        o.z = f2bf(acc[m][n][2] + badd);
        o.w = f2bf(acc[m][n][3] + badd);
        *(ushort4*)&Cvt[b * 2097152 + (long long)col * 2048 + srw] = o;
      }
    }
  }
}

// ---------------------------------------------------------------------------
// pv_gemm: 128x128 tile, 2-phase, 64 KB LDS, 2 blocks/CU (r9, proven).
// ---------------------------------------------------------------------------
template<int RX, int RY>
__global__ __launch_bounds__(512, 4)
void pv_gemm(const ushort_t* __restrict__ A, long long sAz, int lda,
             const ushort_t* __restrict__ Bm, long long sBz, int ldb,
             float* __restrict__ C0, long long sCz, int ldc, int K)
{
  constexpr int SLOT = 8192;
  constexpr int BUF  = 2 * SLOT;
  __shared__ ushort_t lds_[2 * BUF] __attribute__((aligned(16)));

  constexpr int BPR = RX * RY;
  const int gx = gridDim.x;
  const int lin = blockIdx.y * gx + blockIdx.x;
  const int xcd = lin & 7, s = lin >> 3;
  const int chunk = s / BPR, idx = s % BPR;
  const int rect = chunk * 8 + xcd;
  const int nrx = gx / RX;
  const int bx = (rect % nrx) * RX + (idx % RX);
  const int by = (rect / nrx) * RY + (idx / RX);

  const int z = blockIdx.z;
  const ushort_t* Ab = A  + (long long)z * sAz + (long long)by * 128 * lda;
  const ushort_t* Bb = Bm + (long long)z * sBz + (long long)bx * 128 * ldb;

  const int tid = threadIdx.x, wid = tid >> 6, lane = tid & 63;
  const int wr = wid >> 2, wc = wid & 3;
  const int l15 = lane & 15;
  const int kx0 = (((lane >> 4) + 0) ^ (l15 & 7)) * 8;
  const int kx1 = (((lane >> 4) + 4) ^ (l15 & 7)) * 8;
  const int srow = lane >> 3;
  const int scol = ((lane & 7) ^ (srow & 7)) * 8;

  const ushort_t* agA = Ab + (long long)(wid * 8 + srow) * lda + scol;
  const ushort_t* agB = Bb + (long long)(wid * 8 + srow) * ldb + scol;
  const long long jA = (long long)64 * lda, jB = (long long)64 * ldb;
  const int ldsA0 = wid * 512;
  const int ldsB0 = SLOT + wid * 512;

  auto stage = [&](const ushort_t* g, long long jstep, int ldsOff) {
#pragma unroll
    for (int j = 0; j < 2; ++j)
      __builtin_amdgcn_global_load_lds(
          (const __attribute__((address_space(1))) void*)(g + j * jstep),
          (__attribute__((address_space(3))) void*)(&lds_[ldsOff + j * 4096]),
          16, 0, 0);
  };

  f32x4 acc[4][2];
#pragma unroll
  for (int m = 0; m < 4; ++m)
#pragma unroll
    for (int n = 0; n < 2; ++n)
#pragma unroll
      for (int j = 0; j < 4; ++j) acc[m][n][j] = 0.f;

  stage(agA, jA, 0 * BUF + ldsA0); agA += 64;
  stage(agB, jB, 0 * BUF + ldsB0); agB += 64;
  stage(agA, jA, 1 * BUF + ldsA0); agA += 64;
  stage(agB, jB, 1 * BUF + ldsB0); agB += 64;
  asm volatile("s_waitcnt vmcnt(4)" ::: "memory");
  __builtin_amdgcn_s_barrier();

  const int NT = K >> 6;
  bf16x8 a0[4], a1[4], bf[2];

  for (int t = 0; t < NT; ++t) {
    const int q = t & 1;
    const ushort_t* Al = &lds_[q * BUF] + wr * 4096;
    const ushort_t* Bl = &lds_[q * BUF + SLOT] + wc * 2048;

#pragma unroll
    for (int m = 0; m < 4; ++m) a0[m] = *(const bf16x8*)(Al + (m * 16 + l15) * 64 + kx0);
#pragma unroll
    for (int n = 0; n < 2; ++n) bf[n] = *(const bf16x8*)(Bl + (n * 16 + l15) * 64 + kx0);
#pragma unroll
    for (int m = 0; m < 4; ++m) a1[m] = *(const bf16x8*)(Al + (m * 16 + l15) * 64 + kx1);
    __builtin_amdgcn_s_barrier();
    __builtin_amdgcn_s_setprio(1);
#pragma unroll
    for (int m = 0; m < 4; ++m)
#pragma unroll
      for (int n = 0; n < 2; ++n)
        acc[m][n] = __builtin_amdgcn_mfma_f32_16x16x32_bf16(a0[m], bf[n], acc[m][n], 0, 0, 0);
    __builtin_amdgcn_s_setprio(0);
    __builtin_amdgcn_s_barrier();

#pragma unroll
    for (int n = 0; n < 2; ++n) bf[n] = *(const bf16x8*)(Bl + (n * 16 + l15) * 64 + kx1);
    asm volatile("s_waitcnt lgkmcnt(0)" ::: "memory");
    __builtin_amdgcn_sched_barrier(0);
    if (t + 2 < NT) {
      stage(agA, jA, q * BUF + ldsA0); agA += 64;
      stage(agB, jB, q * BUF + ldsB0); agB += 64;
    }
    __builtin_amdgcn_s_barrier();
    __builtin_amdgcn_s_setprio(1);
#pragma unroll
    for (int m = 0; m < 4; ++m)
#pragma unroll
      for (int n = 0; n < 2; ++n)
        acc[m][n] = __builtin_amdgcn_mfma_f32_16x16x32_bf16(a1[m], bf[n], acc[m][n], 0, 0, 0);
    __builtin_amdgcn_s_setprio(0);
    if (t < NT - 2)       asm volatile("s_waitcnt vmcnt(4)" ::: "memory");
    else if (t == NT - 2) asm volatile("s_waitcnt vmcnt(0)" ::: "memory");
    __builtin_amdgcn_s_barrier();
  }

  const int r4 = (lane >> 4) * 4;
  const long long crow0 = (long long)by * 128 + wr * 64;
  const int ccol0 = bx * 128 + wc * 32;
#pragma unroll
  for (int n = 0; n < 2; ++n) {
    const int cg = ccol0 + n * 16 + l15;
#pragma unroll
    for (int m = 0; m < 4; ++m)
#pragma unroll
      for (int j = 0; j < 4; ++j) {
        const long long rg = crow0 + m * 16 + r4 + j;
        C0[(long long)z * sCz + rg * ldc + cg] = acc[m][n][j];
      }
  }
}

// ---------------------------------------------------------------------------
// qk_gemm: 256x256 tile, 4-phase; fp16 scores out (r8/r9, proven).
// ---------------------------------------------------------------------------
__global__ __launch_bounds__(512, 1)
void qk_gemm(const ushort_t* __restrict__ A, long long sAz, int lda,
             const ushort_t* __restrict__ Bm, long long sBz, int ldb,
             _Float16* __restrict__ C, long long sCz, int ldc,
             int K, float scale)
{
  constexpr int AH = 8192, BH = 8192, BUF = 2 * AH + 2 * BH;
  constexpr int RX = 4, RY = 2, BPR = RX * RY;
  __shared__ ushort_t lds_[2 * BUF] __attribute__((aligned(16)));

  const int gx = gridDim.x;
  const int lin = blockIdx.y * gx + blockIdx.x;
  const int xcd = lin & 7, s = lin >> 3;
  const int chunk = s / BPR, idx = s % BPR;
  const int rect = chunk * 8 + xcd;
  const int nrx = gx / RX;
  const int bx = (rect % nrx) * RX + (idx % RX);
  const int by = (rect / nrx) * RY + (idx / RX);

  const int z = blockIdx.z;
  const ushort_t* Ab = A  + (long long)z * sAz + (long long)by * 256 * lda;
  const ushort_t* Bb = Bm + (long long)z * sBz + (long long)bx * 256 * ldb;

  const int tid = threadIdx.x, wid = tid >> 6, lane = tid & 63;
  const int wr = wid >> 2, wc = wid & 3;
  const int l15 = lane & 15;
  const int kx0 = (((lane >> 4) + 0) ^ (l15 & 7)) * 8;
  const int kx1 = (((lane >> 4) + 4) ^ (l15 & 7)) * 8;
  const int srow = lane >> 3;
  const int scol = ((lane & 7) ^ (srow & 7)) * 8;

  const ushort_t* agA = Ab + (long long)(wid * 16 + srow) * lda + scol;
  const ushort_t* agB = Bb + (long long)(wid * 16 + srow) * ldb + scol;

  auto stageA = [&](int q) {
#pragma unroll
    for (int h = 0; h < 2; ++h)
#pragma unroll
      for (int j = 0; j < 2; ++j)
        __builtin_amdgcn_global_load_lds(
            (const __attribute__((address_space(1))) void*)(agA + (long long)(h * 128 + j * 8) * lda),
            (__attribute__((address_space(3))) void*)
              (&lds_[q * BUF + h * AH + (wid * 128 + j * 64) * 8]),
            16, 0, 0);
  };
  auto stageB = [&](int q) {
#pragma unroll
    for (int h = 0; h < 2; ++h)
#pragma unroll
      for (int j = 0; j < 2; ++j)
        __builtin_amdgcn_global_load_lds(
            (const __attribute__((address_space(1))) void*)(agB + (long long)(h * 128 + j * 8) * ldb),
            (__attribute__((address_space(3))) void*)
              (&lds_[q * BUF + 2 * AH + h * BH + (wid * 128 + j * 64) * 8]),
            16, 0, 0);
  };

  f32x4 acc[8][4];
#pragma unroll
  for (int m = 0; m < 8; ++m)
#pragma unroll
    for (int n = 0; n < 4; ++n)
#pragma unroll
      for (int j = 0; j < 4; ++j) acc[m][n][j] = 0.f;

  stageA(0); stageB(0); agA += 64; agB += 64;
  stageA(1); stageB(1); agA += 64; agB += 64;
  asm volatile("s_waitcnt vmcnt(8)" ::: "memory");
  __builtin_amdgcn_s_barrier();

  const int NT = K >> 6;
  bf16x8 af[4], bf[4];

  for (int t = 0; t < NT; ++t) {
    const int q = t & 1;
    const ushort_t* Al = &lds_[q * BUF + wr * AH];
    const ushort_t* Bl = &lds_[q * BUF + 2 * AH + (wc >> 1) * BH + (wc & 1) * 4096];

    // ph1
#pragma unroll
    for (int n = 0; n < 4; ++n) bf[n] = *(const bf16x8*)(Bl + (n * 16 + l15) * 64 + kx0);
#pragma unroll
    for (int m = 0; m < 4; ++m) af[m] = *(const bf16x8*)(Al + (m * 16 + l15) * 64 + kx0);
    __builtin_amdgcn_s_barrier();
    __builtin_amdgcn_s_setprio(1);
#pragma unroll
    for (int m = 0; m < 4; ++m)
#pragma unroll
      for (int n = 0; n < 4; ++n)
        acc[m][n] = __builtin_amdgcn_mfma_f32_16x16x32_bf16(af[m], bf[n], acc[m][n], 0, 0, 0);
    __builtin_amdgcn_s_setprio(0);
    __builtin_amdgcn_s_barrier();

    // ph2
#pragma unroll
    for (int m = 0; m < 4; ++m) af[m] = *(const bf16x8*)(Al + ((4 + m) * 16 + l15) * 64 + kx0);
    __builtin_amdgcn_s_barrier();
    __builtin_amdgcn_s_setprio(1);
#pragma unroll
    for (int m = 0; m < 4; ++m)
#pragma unroll
      for (int n = 0; n < 4; ++n)
        acc[4 + m][n] = __builtin_amdgcn_mfma_f32_16x16x32_bf16(af[m], bf[n], acc[4 + m][n], 0, 0, 0);
    __builtin_amdgcn_s_setprio(0);
    __builtin_amdgcn_s_barrier();

    // ph3
#pragma unroll
    for (int n = 0; n < 4; ++n) bf[n] = *(const bf16x8*)(Bl + (n * 16 + l15) * 64 + kx1);
#pragma unroll
    for (int m = 0; m < 4; ++m) af[m] = *(const bf16x8*)(Al + (m * 16 + l15) * 64 + kx1);
    __builtin_amdgcn_s_barrier();
    __builtin_amdgcn_s_setprio(1);
#pragma unroll
    for (int m = 0; m < 4; ++m)
#pragma unroll
      for (int n = 0; n < 4; ++n)
        acc[m][n] = __builtin_amdgcn_mfma_f32_16x16x32_bf16(af[m], bf[n], acc[m][n], 0, 0, 0);
    __builtin_amdgcn_s_setprio(0);
    __builtin_amdgcn_s_barrier();

    // ph4 + staged prefetch after lgkm drain
#pragma unroll
    for (int m = 0; m < 4; ++m) af[m] = *(const bf16x8*)(Al + ((4 + m) * 16 + l15) * 64 + kx1);
    asm volatile("s_waitcnt lgkmcnt(0)" ::: "memory");
    __builtin_amdgcn_sched_barrier(0);
    if (t + 2 < NT) { stageA(q); stageB(q); agA += 64; agB += 64; }
    __builtin_amdgcn_s_barrier();
    __builtin_amdgcn_s_setprio(1);
#pragma unroll
    for (int m = 0; m < 4; ++m)
#pragma unroll
      for (int n = 0; n < 4; ++n)
        acc[4 + m][n] = __builtin_amdgcn_mfma_f32_16x16x32_bf16(af[m], bf[n], acc[4 + m][n], 0, 0, 0);
    __builtin_amdgcn_s_setprio(0);
    if (t < NT - 2)       asm volatile("s_waitcnt vmcnt(8)" ::: "memory");
    else if (t == NT - 2) asm volatile("s_waitcnt vmcnt(0)" ::: "memory");
    __builtin_amdgcn_s_barrier();
  }

  const int r4 = (lane >> 4) * 4;
  const long long crow0 = (long long)by * 256 + wr * 128;
  const int ccol0 = bx * 256 + wc * 64;
#pragma unroll
  for (int n = 0; n < 4; ++n) {
    const int cg = ccol0 + n * 16 + l15;
#pragma unroll
    for (int m = 0; m < 8; ++m)
#pragma unroll
      for (int j = 0; j < 4; ++j) {
        const long long rg = crow0 + m * 16 + r4 + j;
        C[(long long)z * sCz + rg * ldc + cg] = (_Float16)(acc[m][n][j] * scale);
      }
  }
}

// ---------------------------------------------------------------------------
// prep_all: one dispatch. Blocks [0,2048): cast x (8.4M f32 -> bf16).
// Blocks [2048,5120): cast Wq|Wk|Wv into w3 [3072][1024] + build bcat.
// ---------------------------------------------------------------------------
__global__ __launch_bounds__(256)
void prep_all(const float* __restrict__ x, ushort_t* __restrict__ xb,
              const float* __restrict__ Wq, const float* __restrict__ Wk,
              const float* __restrict__ Wv, const float* __restrict__ bq,
              const float* __restrict__ bk, const float* __restrict__ bv,
              ushort_t* __restrict__ w3, float* __restrict__ bcat)
{
  if (blockIdx.x < 2048) {
    // x cast: 2048 blocks x 256 thr x 4 elems x 4 iters = 8388608
    const long long nx = 8388608LL;
    long long i = ((long long)blockIdx.x * 256 + threadIdx.x) * 4;
    const long long stride = 2048LL * 256 * 4;
    for (; i < nx; i += stride) {
      const float4 v = *(const float4*)&x[i];
      ushort4 o;
      o.x = f2bf(v.x); o.y = f2bf(v.y); o.z = f2bf(v.z); o.w = f2bf(v.w);
      *(ushort4*)&xb[i] = o;
    }
  } else {
    const int wb = blockIdx.x - 2048;            // 0..3071
    const int which = wb >> 10;
    const float* W = (which == 0) ? Wq : (which == 1) ? Wk : Wv;
    const long long i = ((long long)(wb & 1023) * 256 + threadIdx.x) * 4;
    const float4 v = *(const float4*)&W[i];
    ushort4 o;
    o.x = f2bf(v.x); o.y = f2bf(v.y); o.z = f2bf(v.z); o.w = f2bf(v.w);
    *(ushort4*)&w3[(long long)which * 1048576 + i] = o;
    const int g = wb * 256 + threadIdx.x;
    if (g < 3072) bcat[g] = (g < 1024) ? bq[g] : (g < 2048) ? bk[g - 1024] : bv[g - 2048];
  }
}

// row softmax over 2048 fp16 -> bf16, one block (256 thr) per row
__global__ __launch_bounds__(256)
void softmax2048(const _Float16* __restrict__ Sc, ushort_t* __restrict__ P)
{
  const long long row = blockIdx.x;
  const _Float16* s = Sc + row * 2048;
  const int tid = threadIdx.x;
  const int wave = tid >> 6, lane = tid & 63;

  const h8 a = *(const h8*)&s[tid * 8];
  float f[8];
#pragma unroll
  for (int i = 0; i < 8; ++i) f[i] = (float)a[i];
  float m = fmaxf(fmaxf(fmaxf(f[0], f[1]), fmaxf(f[2], f[3])),
                  fmaxf(fmaxf(f[4], f[5]), fmaxf(f[6], f[7])));
#pragma unroll
  for (int off = 32; off > 0; off >>= 1) m = fmaxf(m, __shfl_xor(m, off));
  __shared__ float redm[4], reds[4];
  if (lane == 0) redm[wave] = m;
  __syncthreads();
  m = fmaxf(fmaxf(redm[0], redm[1]), fmaxf(redm[2], redm[3]));

  float e[8];
#pragma unroll
  for (int i = 0; i < 8; ++i) e[i] = __expf(f[i] - m);
  float sum = ((e[0] + e[1]) + (e[2] + e[3])) + ((e[4] + e[5]) + (e[6] + e[7]));
#pragma unroll
  for (int off = 32; off > 0; off >>= 1) sum += __shfl_xor(sum, off);
  if (lane == 0) reds[wave] = sum;
  __syncthreads();
  sum = (reds[0] + reds[1]) + (reds[2] + reds[3]);
  const float inv = 1.0f / sum;

  short8v o;
#pragma unroll
  for (int i = 0; i < 8; ++i) o[i] = (short)f2bf(e[i] * inv);
  *(short8v*)&P[row * 2048 + tid * 8] = o;
}

// ---------------------------------------------------------------------------
extern "C" void kernel_launch(void* const* d_in, const int* in_sizes, int n_in,
                              void* d_out, int out_size, void* d_ws, size_t ws_size,
                              hipStream_t stream)
{
  constexpr int B = 4, S = 2048, D = 1024;
  constexpr long long MT = (long long)B * S;
  constexpr long long SD = (long long)S * D;
  constexpr long long SS = (long long)S * S;

  const float* x  = (const float*)d_in[0];
  const float* Wq = (const float*)d_in[1];
  const float* bq = (const float*)d_in[2];
  const float* Wk = (const float*)d_in[3];
  const float* bk = (const float*)d_in[4];
  const float* Wv = (const float*)d_in[5];
  const float* bv = (const float*)d_in[6];
  float* out = (float*)d_out;

  // ws layout (bytes)
  char* base = (char*)d_ws;
  ushort_t*  q       = (ushort_t*)(base);               // 16777216
  ushort_t*  k       = (ushort_t*)(base + 16777216);    // 16777216
  ushort_t*  vt      = (ushort_t*)(base + 33554432);    // 16777216  [4][1024][2048]
  _Float16*  scores  = (_Float16*)(base + 50331648);    // 33554432  fp16
  ushort_t*  P       = (ushort_t*)(base + 117440512);   // 33554432
  ushort_t*  xb      = (ushort_t*)(base + 83886080);    // 16777216
  ushort_t*  w3      = (ushort_t*)(base + 100663296);   // 6291456
  float*     bcat    = (float*)   (base + 106954752);   // 12288

  // 1) fused prep: x cast + W cast + bias concat (one dispatch)
  prep_all<<<5120, 256, 0, stream>>>(x, xb, Wq, Wk, Wv, bq, bk, bv, w3, bcat);

  // 2) fused QKV projection (m97 structure, 4 blocks/CU) -> q, k, vt
  proj_gemm<<<dim3(24, 64, 1), 256, 0, stream>>>(
      xb, D, w3, D, q, k, vt, D, bcat);

  // 3) QK^T: scores[z] = (q @ k^T) / 32  (fp16 out)
  qk_gemm<<<dim3(8, 8, 4), 512, 0, stream>>>(
      q, SD, D, k, SD, D, scores, SS, S, D, 0.03125f);

  // 4) softmax rows (fp16 in, bf16 out)
  softmax2048<<<MT, 256, 0, stream>>>(scores, P);

  // 5) PV: out[z] = P @ vt^T
  pv_gemm<2, 4><<<dim3(8, 16, 4), 512, 0, stream>>>(
      P, SS, S, vt, (long long)D * S, S, out, SD, D, S);
}